// Round 3
// baseline (1489.209 us; speedup 1.0000x reference)
//
#include <hip/hip_runtime.h>
#include <math.h>

static constexpr int N_NODES = 100000;
static constexpr int N_EDGES = 3200000;
static constexpr int F_INC   = 256;
static constexpr int HIDC    = 16;
static constexpr int NCLS    = 32;

static constexpr int BNODES  = 256;                      // nodes per bucket
static constexpr int NBKT    = (N_NODES + BNODES - 1) / BNODES;  // 391
static constexpr int CAP     = 9216;                     // slab slots per bucket (mean 8184, +11 sigma)
static constexpr int CHUNK   = 8192;                     // edges per bucketing block
static constexpr int NCHUNK  = (N_EDGES + CHUNK - 1) / CHUNK;    // 391

__global__ void k_zero_cur(int* gcur) {
    int i = blockIdx.x * blockDim.x + threadIdx.x;
    if (i < NBKT) gcur[i] = 0;
}

// Bin a chunk of 8192 edges by dst bucket in LDS, then flush bucket-sorted runs to the slab.
__global__ __launch_bounds__(256) void k_bucket(const int* __restrict__ src,
                                                const int* __restrict__ dst,
                                                int* gcur, unsigned int* __restrict__ slab) {
    __shared__ int hist[NBKT];
    __shared__ int ofs[NBKT];
    __shared__ int place[NBKT];
    __shared__ int gbase[NBKT];
    __shared__ unsigned int staging[CHUNK];
    __shared__ unsigned short bid[CHUNK];
    int tid = threadIdx.x;
    int e0 = blockIdx.x * CHUNK;
    int n = min(CHUNK, N_EDGES - e0);
    for (int b = tid; b < NBKT; b += 256) hist[b] = 0;
    __syncthreads();
    unsigned int pay[32];
    int bk[32];
    #pragma unroll
    for (int r = 0; r < 32; ++r) {
        int i = r * 256 + tid;
        bk[r] = -1;
        if (i < n) {
            int e = e0 + i;
            int s = src[e];
            int t = dst[e];
            int b = t >> 8;
            pay[r] = (unsigned)s | ((unsigned)(t & 255) << 24);
            bk[r] = b;
            atomicAdd(&hist[b], 1);
        }
    }
    __syncthreads();
    if (tid == 0) {          // serial exclusive scan over 391 buckets
        int acc = 0;
        for (int b = 0; b < NBKT; ++b) { ofs[b] = acc; acc += hist[b]; }
    }
    __syncthreads();
    for (int b = tid; b < NBKT; b += 256) {
        place[b] = ofs[b];
        int c = hist[b];
        gbase[b] = c ? atomicAdd(&gcur[b], c) : 0;
    }
    __syncthreads();
    #pragma unroll
    for (int r = 0; r < 32; ++r) {
        if (bk[r] >= 0) {
            int p = atomicAdd(&place[bk[r]], 1);
            staging[p] = pay[r];
            bid[p] = (unsigned short)bk[r];
        }
    }
    __syncthreads();
    for (int i = tid; i < n; i += 256) {
        int b = bid[i];
        int gp = gbase[b] + (i - ofs[b]);
        if (gp < CAP) slab[(size_t)b * CAP + gp] = staging[i];
    }
}

// Per-bucket in-degree histogram -> deg_inv_sqrt. No global atomics.
__global__ __launch_bounds__(512) void k_dis(const int* __restrict__ gcur,
                                             const unsigned int* __restrict__ slab,
                                             float* __restrict__ dis) {
    __shared__ int hist[BNODES];
    int tid = threadIdx.x, b = blockIdx.x;
    if (tid < BNODES) hist[tid] = 0;
    __syncthreads();
    int count = min(gcur[b], CAP);
    const unsigned int* sl = slab + (size_t)b * CAP;
    for (int i = tid; i < count; i += 512) atomicAdd(&hist[sl[i] >> 24], 1);
    __syncthreads();
    int node = b * BNODES + tid;
    if (tid < BNODES && node < N_NODES) dis[node] = rsqrtf((float)hist[tid] + 1.0f);
}

__global__ __launch_bounds__(256) void k_linear1(const float* __restrict__ x,
                                                 const float* __restrict__ W1,
                                                 float* __restrict__ h) {
    __shared__ float Ws[F_INC * HIDC];
    for (int i = threadIdx.x; i < F_INC * HIDC; i += 256) Ws[i] = W1[i];
    __syncthreads();
    int n = blockIdx.x * blockDim.x + threadIdx.x;
    if (n >= N_NODES) return;
    float acc[HIDC];
    #pragma unroll
    for (int j = 0; j < HIDC; ++j) acc[j] = 0.f;
    const float4* xr = (const float4*)(x + (size_t)n * F_INC);
    for (int k4 = 0; k4 < F_INC / 4; ++k4) {
        float4 v = xr[k4];
        const float* w = &Ws[k4 * 4 * HIDC];
        #pragma unroll
        for (int j = 0; j < HIDC; ++j)
            acc[j] += v.x * w[j] + v.y * w[HIDC + j] + v.z * w[2 * HIDC + j] + v.w * w[3 * HIDC + j];
    }
    float4* o = (float4*)(h + (size_t)n * HIDC);
    #pragma unroll
    for (int j4 = 0; j4 < HIDC / 4; ++j4)
        o[j4] = make_float4(acc[4 * j4], acc[4 * j4 + 1], acc[4 * j4 + 2], acc[4 * j4 + 3]);
}

// Bucket-local aggregation into an LDS tile:
// agg[n,:] = dis[n] * ( dis[n]*h[n,:] + sum_{s in in(n)} dis[s]*h[s,:] )
template<int D>
__global__ __launch_bounds__(512) void k_agg(const int* __restrict__ gcur,
                                             const unsigned int* __restrict__ slab,
                                             const float* __restrict__ dis,
                                             const float* __restrict__ h,
                                             float* __restrict__ agg) {
    __shared__ float tile[BNODES * (D + 1)];
    int tid = threadIdx.x, b = blockIdx.x;
    int node0 = b * BNODES;
    for (int i = tid; i < BNODES * D; i += 512) {
        int dl = i / D, d = i - dl * D;
        int nn = node0 + dl;
        tile[dl * (D + 1) + d] = (nn < N_NODES) ? dis[nn] * h[(size_t)nn * D + d] : 0.f;
    }
    __syncthreads();
    int count = min(gcur[b], CAP);
    const unsigned int* sl = slab + (size_t)b * CAP;
    for (int i = tid; i < count * D; i += 512) {
        int e = i / D, d = i - e * D;
        unsigned int v = sl[e];
        int s = v & 0xFFFFFF;
        int dl = v >> 24;
        atomicAdd(&tile[dl * (D + 1) + d], dis[s] * h[(size_t)s * D + d]);
    }
    __syncthreads();
    for (int i = tid; i < BNODES * D; i += 512) {
        int dl = i / D, d = i - dl * D;
        int nn = node0 + dl;
        if (nn < N_NODES) agg[(size_t)nn * D + d] = tile[dl * (D + 1) + d] * dis[nn];
    }
}

// Layer-3: bucket aggregation (D=32) fused with bias + ELU + log_softmax.
__global__ __launch_bounds__(512) void k_aggfinal(const int* __restrict__ gcur,
                                                  const unsigned int* __restrict__ slab,
                                                  const float* __restrict__ dis,
                                                  const float* __restrict__ h,
                                                  const float* __restrict__ bias,
                                                  float* __restrict__ out) {
    __shared__ float tile[BNODES * 33];
    __shared__ float lse[BNODES];
    __shared__ float bs[NCLS];
    int tid = threadIdx.x, b = blockIdx.x;
    int node0 = b * BNODES;
    if (tid < NCLS) bs[tid] = bias[tid];
    for (int i = tid; i < BNODES * 32; i += 512) {
        int dl = i >> 5, d = i & 31;
        int nn = node0 + dl;
        tile[dl * 33 + d] = (nn < N_NODES) ? dis[nn] * h[(size_t)nn * 32 + d] : 0.f;
    }
    __syncthreads();
    int count = min(gcur[b], CAP);
    const unsigned int* sl = slab + (size_t)b * CAP;
    for (int i = tid; i < count * 32; i += 512) {
        int e = i >> 5, d = i & 31;
        unsigned int v = sl[e];
        int s = v & 0xFFFFFF;
        int dl = v >> 24;
        atomicAdd(&tile[dl * 33 + d], dis[s] * h[(size_t)s * 32 + d]);
    }
    __syncthreads();
    if (tid < BNODES) {
        int nn = node0 + tid;
        if (nn < N_NODES) {
            float dn = dis[nn];
            float r[NCLS];
            float m = -1e30f;
            #pragma unroll
            for (int d = 0; d < NCLS; ++d) {
                float t = tile[tid * 33 + d] * dn + bs[d];
                t = t > 0.f ? t : expm1f(t);
                r[d] = t;
                m = fmaxf(m, t);
            }
            float ssum = 0.f;
            #pragma unroll
            for (int d = 0; d < NCLS; ++d) { tile[tid * 33 + d] = r[d]; ssum += expf(r[d] - m); }
            lse[tid] = logf(ssum) + m;
        }
    }
    __syncthreads();
    for (int i = tid; i < BNODES * 32; i += 512) {
        int dl = i >> 5, d = i & 31;
        int nn = node0 + dl;
        if (nn < N_NODES) out[(size_t)nn * 32 + d] = tile[dl * 33 + d] - lse[dl];
    }
}

template<int DIN, int DOUT>
__global__ __launch_bounds__(256) void k_finlin(const float* __restrict__ agg,
                                                const float* __restrict__ bias,
                                                const float* __restrict__ W,
                                                float* __restrict__ hout) {
    __shared__ float Ws[DIN * DOUT];
    __shared__ float bs[DIN];
    for (int i = threadIdx.x; i < DIN * DOUT; i += 256) Ws[i] = W[i];
    if (threadIdx.x < DIN) bs[threadIdx.x] = bias[threadIdx.x];
    __syncthreads();
    int n = blockIdx.x * blockDim.x + threadIdx.x;
    if (n >= N_NODES) return;
    float act[DIN];
    const float4* ar = (const float4*)(agg + (size_t)n * DIN);
    #pragma unroll
    for (int k4 = 0; k4 < DIN / 4; ++k4) {
        float4 v = ar[k4];
        float t0 = v.x + bs[4 * k4 + 0]; act[4 * k4 + 0] = t0 > 0.f ? t0 : expm1f(t0);
        float t1 = v.y + bs[4 * k4 + 1]; act[4 * k4 + 1] = t1 > 0.f ? t1 : expm1f(t1);
        float t2 = v.z + bs[4 * k4 + 2]; act[4 * k4 + 2] = t2 > 0.f ? t2 : expm1f(t2);
        float t3 = v.w + bs[4 * k4 + 3]; act[4 * k4 + 3] = t3 > 0.f ? t3 : expm1f(t3);
    }
    float acc[DOUT];
    #pragma unroll
    for (int j = 0; j < DOUT; ++j) acc[j] = 0.f;
    for (int k = 0; k < DIN; ++k) {
        float a = act[k];
        #pragma unroll
        for (int j = 0; j < DOUT; ++j) acc[j] += a * Ws[k * DOUT + j];
    }
    float4* o = (float4*)(hout + (size_t)n * DOUT);
    #pragma unroll
    for (int j4 = 0; j4 < DOUT / 4; ++j4)
        o[j4] = make_float4(acc[4 * j4], acc[4 * j4 + 1], acc[4 * j4 + 2], acc[4 * j4 + 3]);
}

extern "C" void kernel_launch(void* const* d_in, const int* in_sizes, int n_in,
                              void* d_out, int out_size, void* d_ws, size_t ws_size,
                              hipStream_t stream) {
    const float* x  = (const float*)d_in[0];
    const int*   ei = (const int*)d_in[1];
    const float* W1 = (const float*)d_in[2];
    const float* b1 = (const float*)d_in[3];
    const float* W2 = (const float*)d_in[4];
    const float* b2 = (const float*)d_in[5];
    const float* W3 = (const float*)d_in[6];
    const float* b3 = (const float*)d_in[7];
    float* out = (float*)d_out;
    const int* src = ei;
    const int* dst = ei + N_EDGES;

    // workspace layout (4-byte elements)
    int* wi = (int*)d_ws;
    int*          gcur = wi;                       // 512 (pad)
    unsigned int* slab = (unsigned int*)(wi + 512);      // NBKT*CAP = 3,603,456
    float* wf = (float*)d_ws;
    float* dis = wf + 512 + (size_t)NBKT * CAP;          // 100,352 (pad)
    float* B   = dis + 100352;                           // N*16 -> 1,638,400
    float* C   = B + 1638400;                            // 1,638,400
    float* H3  = C + 1638400;                            // N*32 -> 3,276,800

    auto blocks = [](long long n) { return (int)((n + 255) / 256); };

    k_zero_cur<<<2, 256, 0, stream>>>(gcur);
    k_bucket<<<NCHUNK, 256, 0, stream>>>(src, dst, gcur, slab);
    k_dis<<<NBKT, 512, 0, stream>>>(gcur, slab, dis);

    // Layer 1: x @ W1 -> bucket-gather -> (bias+ELU) @ W2
    k_linear1<<<blocks(N_NODES), 256, 0, stream>>>(x, W1, B);
    k_agg<16><<<NBKT, 512, 0, stream>>>(gcur, slab, dis, B, C);
    k_finlin<16, 16><<<blocks(N_NODES), 256, 0, stream>>>(C, b1, W2, B);

    // Layer 2
    k_agg<16><<<NBKT, 512, 0, stream>>>(gcur, slab, dis, B, C);
    k_finlin<16, 32><<<blocks(N_NODES), 256, 0, stream>>>(C, b2, W3, H3);

    // Layer 3: aggregation fused with bias + ELU + log_softmax
    k_aggfinal<<<NBKT, 512, 0, stream>>>(gcur, slab, dis, H3, b3, out);
}

// Round 4
// 275.815 us; speedup vs baseline: 5.3993x; 5.3993x over previous
//
#include <hip/hip_runtime.h>
#include <math.h>

static constexpr int N_NODES = 100000;
static constexpr int N_EDGES = 3200000;
static constexpr int F_INC   = 256;
static constexpr int HIDC    = 16;
static constexpr int NCLS    = 32;

static constexpr int BNODES  = 256;                              // nodes per bucket
static constexpr int NBKT    = (N_NODES + BNODES - 1) / BNODES;  // 391
static constexpr int CAP     = 9216;                             // slab slots per bucket
static constexpr int CHUNK   = 4096;                             // edges per bucketing block
static constexpr int NCHUNK  = (N_EDGES + CHUNK - 1) / CHUNK;    // 782

__global__ void k_zero_cur(int* gcur) {
    int i = threadIdx.x;
    if (i < NBKT) gcur[i] = 0;
}

// Bin a chunk of 4096 edges by dst bucket in LDS, flush bucket-sorted runs to the slab.
__global__ __launch_bounds__(256) void k_bucket(const int* __restrict__ src,
                                                const int* __restrict__ dst,
                                                int* gcur, unsigned int* __restrict__ slab) {
    __shared__ int hist[512];
    __shared__ int sc[512];
    __shared__ int place[512];
    __shared__ int gbase[512];
    __shared__ unsigned int staging[CHUNK];
    __shared__ unsigned short bid[CHUNK];
    int tid = threadIdx.x;
    int e0 = blockIdx.x * CHUNK;
    int n = min(CHUNK, N_EDGES - e0);
    hist[tid] = 0; hist[tid + 256] = 0;
    __syncthreads();
    unsigned int pay[16];
    int bk[16];
    #pragma unroll
    for (int r = 0; r < 16; ++r) {
        int i = r * 256 + tid;
        bk[r] = -1;
        if (i < n) {
            int e = e0 + i;
            int s = src[e];
            int t = dst[e];
            int b = t >> 8;
            pay[r] = (unsigned)s | ((unsigned)(t & 255) << 24);
            bk[r] = b;
            atomicAdd(&hist[b], 1);
        }
    }
    __syncthreads();
    sc[tid] = hist[tid]; sc[tid + 256] = hist[tid + 256];
    __syncthreads();
    // Hillis-Steele inclusive scan over 512 entries, 2 per thread
    for (int off = 1; off < 512; off <<= 1) {
        int i0 = tid, i1 = tid + 256;
        int v0 = (i0 >= off) ? sc[i0 - off] : 0;
        int v1 = (i1 >= off) ? sc[i1 - off] : 0;
        __syncthreads();
        sc[i0] += v0; sc[i1] += v1;
        __syncthreads();
    }
    // exclusive offset = inclusive - self
    {
        int b0 = tid, b1 = tid + 256;
        int o0 = sc[b0] - hist[b0];
        int o1 = sc[b1] - hist[b1];
        place[b0] = o0; place[b1] = o1;
        sc[b0] = o0; sc[b1] = o1;          // sc now holds exclusive offsets
        if (b0 < NBKT && hist[b0]) gbase[b0] = atomicAdd(&gcur[b0], hist[b0]);
        if (b1 < NBKT && hist[b1]) gbase[b1] = atomicAdd(&gcur[b1], hist[b1]);
    }
    __syncthreads();
    #pragma unroll
    for (int r = 0; r < 16; ++r) {
        if (bk[r] >= 0) {
            int p = atomicAdd(&place[bk[r]], 1);
            staging[p] = pay[r];
            bid[p] = (unsigned short)bk[r];
        }
    }
    __syncthreads();
    for (int i = tid; i < n; i += 256) {
        int b = bid[i];
        int gp = gbase[b] + (i - sc[b]);
        if (gp < CAP) slab[(size_t)b * CAP + gp] = staging[i];
    }
}

// Per bucket: histogram local dst, scan, reorder in LDS, write back IN PLACE
// (coalesced, sorted by dst). Emits rowptr/cnt/dis.
__global__ __launch_bounds__(512) void k_csr(const int* __restrict__ gcur,
                                             unsigned int* __restrict__ slab,
                                             int* __restrict__ rowptr,
                                             int* __restrict__ cnt,
                                             float* __restrict__ dis) {
    __shared__ int hist[BNODES];
    __shared__ int lofs[BNODES];
    __shared__ int place[BNODES];
    __shared__ unsigned int reord[CAP];
    int tid = threadIdx.x, b = blockIdx.x;
    if (tid < BNODES) hist[tid] = 0;
    __syncthreads();
    int count = min(gcur[b], CAP);
    unsigned int* sl = slab + (size_t)b * CAP;
    for (int i = tid; i < count; i += 512) atomicAdd(&hist[sl[i] >> 24], 1);
    __syncthreads();
    if (tid < BNODES) lofs[tid] = hist[tid];
    __syncthreads();
    for (int off = 1; off < BNODES; off <<= 1) {   // inclusive scan
        int v = 0;
        if (tid < BNODES && tid >= off) v = lofs[tid - off];
        __syncthreads();
        if (tid < BNODES) lofs[tid] += v;
        __syncthreads();
    }
    if (tid < BNODES) {
        int ex = lofs[tid] - hist[tid];            // exclusive
        lofs[tid] = ex;
        place[tid] = ex;
        int node = b * BNODES + tid;
        if (node < N_NODES) {
            rowptr[node] = b * CAP + ex;
            cnt[node] = hist[tid];
            dis[node] = rsqrtf((float)hist[tid] + 1.0f);
        }
    }
    __syncthreads();
    for (int i = tid; i < count; i += 512) {
        unsigned int v = sl[i];
        int dl = v >> 24;
        int p = atomicAdd(&place[dl], 1);
        reord[p] = v & 0xFFFFFFu;                  // plain src index
    }
    __syncthreads();
    for (int i = tid; i < count; i += 512) sl[i] = reord[i];
}

__global__ __launch_bounds__(256) void k_linear1(const float* __restrict__ x,
                                                 const float* __restrict__ W1,
                                                 float* __restrict__ h) {
    __shared__ float Ws[F_INC * HIDC];
    for (int i = threadIdx.x; i < F_INC * HIDC; i += 256) Ws[i] = W1[i];
    __syncthreads();
    int n = blockIdx.x * blockDim.x + threadIdx.x;
    if (n >= N_NODES) return;
    float acc[HIDC];
    #pragma unroll
    for (int j = 0; j < HIDC; ++j) acc[j] = 0.f;
    const float4* xr = (const float4*)(x + (size_t)n * F_INC);
    for (int k4 = 0; k4 < F_INC / 4; ++k4) {
        float4 v = xr[k4];
        const float* w = &Ws[k4 * 4 * HIDC];
        #pragma unroll
        for (int j = 0; j < HIDC; ++j)
            acc[j] += v.x * w[j] + v.y * w[HIDC + j] + v.z * w[2 * HIDC + j] + v.w * w[3 * HIDC + j];
    }
    float4* o = (float4*)(h + (size_t)n * HIDC);
    #pragma unroll
    for (int j4 = 0; j4 < HIDC / 4; ++j4)
        o[j4] = make_float4(acc[4 * j4], acc[4 * j4 + 1], acc[4 * j4 + 2], acc[4 * j4 + 3]);
}

// gather aggregation: agg[n,d] = dis[n] * (dis[n]*h[n,d] + sum_{s in in(n)} dis[s]*h[s,d])
template<int D>
__global__ __launch_bounds__(256) void k_gather(const int* __restrict__ rowptr,
                                                const int* __restrict__ cnt,
                                                const unsigned int* __restrict__ csr,
                                                const float* __restrict__ dis,
                                                const float* __restrict__ h,
                                                float* __restrict__ agg) {
    int idx = blockIdx.x * blockDim.x + threadIdx.x;
    int n = idx / D;
    int d = idx - n * D;
    if (n >= N_NODES) return;
    float dn = dis[n];
    int base = rowptr[n];
    int deg = cnt[n];
    float acc = dn * h[(size_t)n * D + d];
    int j = 0;
    for (; j + 3 < deg; j += 4) {
        int s0 = csr[base + j];
        int s1 = csr[base + j + 1];
        int s2 = csr[base + j + 2];
        int s3 = csr[base + j + 3];
        float v0 = dis[s0] * h[(size_t)s0 * D + d];
        float v1 = dis[s1] * h[(size_t)s1 * D + d];
        float v2 = dis[s2] * h[(size_t)s2 * D + d];
        float v3 = dis[s3] * h[(size_t)s3 * D + d];
        acc += (v0 + v1) + (v2 + v3);
    }
    for (; j < deg; ++j) {
        int s = csr[base + j];
        acc += dis[s] * h[(size_t)s * D + d];
    }
    agg[idx] = dn * acc;
}

// layer-3 gather fused with bias + ELU + log_softmax (32-lane groups)
__global__ __launch_bounds__(256) void k_gather32_final(const int* __restrict__ rowptr,
                                                        const int* __restrict__ cnt,
                                                        const unsigned int* __restrict__ csr,
                                                        const float* __restrict__ dis,
                                                        const float* __restrict__ h,
                                                        const float* __restrict__ bias,
                                                        float* __restrict__ out) {
    int idx = blockIdx.x * blockDim.x + threadIdx.x;
    int n = idx / NCLS;
    int d = idx - n * NCLS;
    if (n >= N_NODES) return;
    float dn = dis[n];
    int base = rowptr[n];
    int deg = cnt[n];
    float acc = dn * h[(size_t)n * NCLS + d];
    int j = 0;
    for (; j + 3 < deg; j += 4) {
        int s0 = csr[base + j];
        int s1 = csr[base + j + 1];
        int s2 = csr[base + j + 2];
        int s3 = csr[base + j + 3];
        float v0 = dis[s0] * h[(size_t)s0 * NCLS + d];
        float v1 = dis[s1] * h[(size_t)s1 * NCLS + d];
        float v2 = dis[s2] * h[(size_t)s2 * NCLS + d];
        float v3 = dis[s3] * h[(size_t)s3 * NCLS + d];
        acc += (v0 + v1) + (v2 + v3);
    }
    for (; j < deg; ++j) {
        int s = csr[base + j];
        acc += dis[s] * h[(size_t)s * NCLS + d];
    }
    float r = dn * acc + bias[d];
    r = r > 0.f ? r : expm1f(r);
    float m = r;
    #pragma unroll
    for (int off = 16; off > 0; off >>= 1) m = fmaxf(m, __shfl_xor(m, off, 32));
    float s = expf(r - m);
    #pragma unroll
    for (int off = 16; off > 0; off >>= 1) s += __shfl_xor(s, off, 32);
    out[idx] = r - (logf(s) + m);
}

template<int DIN, int DOUT>
__global__ __launch_bounds__(256) void k_finlin(const float* __restrict__ agg,
                                                const float* __restrict__ bias,
                                                const float* __restrict__ W,
                                                float* __restrict__ hout) {
    __shared__ float Ws[DIN * DOUT];
    __shared__ float bs[DIN];
    for (int i = threadIdx.x; i < DIN * DOUT; i += 256) Ws[i] = W[i];
    if (threadIdx.x < DIN) bs[threadIdx.x] = bias[threadIdx.x];
    __syncthreads();
    int n = blockIdx.x * blockDim.x + threadIdx.x;
    if (n >= N_NODES) return;
    float act[DIN];
    const float4* ar = (const float4*)(agg + (size_t)n * DIN);
    #pragma unroll
    for (int k4 = 0; k4 < DIN / 4; ++k4) {
        float4 v = ar[k4];
        float t0 = v.x + bs[4 * k4 + 0]; act[4 * k4 + 0] = t0 > 0.f ? t0 : expm1f(t0);
        float t1 = v.y + bs[4 * k4 + 1]; act[4 * k4 + 1] = t1 > 0.f ? t1 : expm1f(t1);
        float t2 = v.z + bs[4 * k4 + 2]; act[4 * k4 + 2] = t2 > 0.f ? t2 : expm1f(t2);
        float t3 = v.w + bs[4 * k4 + 3]; act[4 * k4 + 3] = t3 > 0.f ? t3 : expm1f(t3);
    }
    float acc[DOUT];
    #pragma unroll
    for (int j = 0; j < DOUT; ++j) acc[j] = 0.f;
    for (int k = 0; k < DIN; ++k) {
        float a = act[k];
        #pragma unroll
        for (int j = 0; j < DOUT; ++j) acc[j] += a * Ws[k * DOUT + j];
    }
    float4* o = (float4*)(hout + (size_t)n * DOUT);
    #pragma unroll
    for (int j4 = 0; j4 < DOUT / 4; ++j4)
        o[j4] = make_float4(acc[4 * j4], acc[4 * j4 + 1], acc[4 * j4 + 2], acc[4 * j4 + 3]);
}

extern "C" void kernel_launch(void* const* d_in, const int* in_sizes, int n_in,
                              void* d_out, int out_size, void* d_ws, size_t ws_size,
                              hipStream_t stream) {
    const float* x  = (const float*)d_in[0];
    const int*   ei = (const int*)d_in[1];
    const float* W1 = (const float*)d_in[2];
    const float* b1 = (const float*)d_in[3];
    const float* W2 = (const float*)d_in[4];
    const float* b2 = (const float*)d_in[5];
    const float* W3 = (const float*)d_in[6];
    const float* b3 = (const float*)d_in[7];
    float* out = (float*)d_out;
    const int* src = ei;
    const int* dst = ei + N_EDGES;

    // workspace layout (4-byte elements)
    int* wi = (int*)d_ws;
    int*          gcur   = wi;                                   // 512
    unsigned int* slab   = (unsigned int*)(wi + 512);            // NBKT*CAP = 3,603,456
    int*          rowptr = wi + 512 + NBKT * CAP;                // 102,400
    int*          cnt    = rowptr + 102400;                      // 102,400
    float* wf = (float*)d_ws;
    float* dis = (float*)(cnt + 102400);                         // 102,400
    float* B   = dis + 102400;                                   // 1,638,400
    float* C   = B + 1638400;                                    // 1,638,400
    float* H3  = C + 1638400;                                    // 3,276,800
    (void)wf; (void)ws_size; (void)n_in; (void)in_sizes; (void)out_size;

    auto blocks = [](long long n) { return (int)((n + 255) / 256); };

    k_zero_cur<<<1, 512, 0, stream>>>(gcur);
    k_bucket<<<NCHUNK, 256, 0, stream>>>(src, dst, gcur, slab);
    k_csr<<<NBKT, 512, 0, stream>>>(gcur, slab, rowptr, cnt, dis);

    // Layer 1: x @ W1 -> gather -> (bias+ELU) @ W2
    k_linear1<<<blocks(N_NODES), 256, 0, stream>>>(x, W1, B);
    k_gather<16><<<blocks((long long)N_NODES * 16), 256, 0, stream>>>(rowptr, cnt, slab, dis, B, C);
    k_finlin<16, 16><<<blocks(N_NODES), 256, 0, stream>>>(C, b1, W2, B);

    // Layer 2: gather -> (bias+ELU) @ W3
    k_gather<16><<<blocks((long long)N_NODES * 16), 256, 0, stream>>>(rowptr, cnt, slab, dis, B, C);
    k_finlin<16, 32><<<blocks(N_NODES), 256, 0, stream>>>(C, b2, W3, H3);

    // Layer 3: gather fused with bias + ELU + log_softmax
    k_gather32_final<<<blocks((long long)N_NODES * 32), 256, 0, stream>>>(rowptr, cnt, slab, dis, H3, b3, out);
}

// Round 5
// 219.497 us; speedup vs baseline: 6.7846x; 1.2566x over previous
//
#include <hip/hip_runtime.h>
#include <math.h>

static constexpr int N_NODES = 100000;
static constexpr int N_EDGES = 3200000;
static constexpr int F_INC   = 256;
static constexpr int HIDC    = 16;
static constexpr int NCLS    = 32;

static constexpr int BNODES  = 256;                              // nodes per bucket
static constexpr int NBKT    = (N_NODES + BNODES - 1) / BNODES;  // 391
static constexpr int CAP     = 9216;                             // slab slots per bucket
static constexpr int CHUNK   = 4096;                             // edges per bucketing block
static constexpr int NCHUNK  = (N_EDGES + CHUNK - 1) / CHUNK;    // 782

// ---- bf16 pair helpers (RNE round) ----
__device__ __forceinline__ unsigned pack_bf2(float a, float b) {
    unsigned ua = __float_as_uint(a);
    unsigned ub = __float_as_uint(b);
    ua = (ua + 0x7FFFu + ((ua >> 16) & 1u)) >> 16;
    ub = (ub + 0x7FFFu + ((ub >> 16) & 1u)) & 0xFFFF0000u;
    return ua | ub;
}
__device__ __forceinline__ float bflo(unsigned v) { return __uint_as_float(v << 16); }
__device__ __forceinline__ float bfhi(unsigned v) { return __uint_as_float(v & 0xFFFF0000u); }
__device__ __forceinline__ float elu1(float t) { return t > 0.f ? t : expm1f(t); }

__global__ void k_zero_cur(int* gcur) {
    int i = threadIdx.x;
    if (i < NBKT) gcur[i] = 0;
}

// Bin a chunk of 4096 edges by dst bucket in LDS, flush bucket-sorted runs to the slab.
__global__ __launch_bounds__(256) void k_bucket(const int* __restrict__ src,
                                                const int* __restrict__ dst,
                                                int* gcur, unsigned int* __restrict__ slab) {
    __shared__ int hist[512];
    __shared__ int sc[512];
    __shared__ int place[512];
    __shared__ int gbase[512];
    __shared__ unsigned int staging[CHUNK];
    __shared__ unsigned short bid[CHUNK];
    int tid = threadIdx.x;
    int e0 = blockIdx.x * CHUNK;
    int n = min(CHUNK, N_EDGES - e0);
    hist[tid] = 0; hist[tid + 256] = 0;
    __syncthreads();
    unsigned int pay[16];
    int bk[16];
    #pragma unroll
    for (int r = 0; r < 16; ++r) {
        int i = r * 256 + tid;
        bk[r] = -1;
        if (i < n) {
            int e = e0 + i;
            int s = src[e];
            int t = dst[e];
            int b = t >> 8;
            pay[r] = (unsigned)s | ((unsigned)(t & 255) << 24);
            bk[r] = b;
            atomicAdd(&hist[b], 1);
        }
    }
    __syncthreads();
    sc[tid] = hist[tid]; sc[tid + 256] = hist[tid + 256];
    __syncthreads();
    for (int off = 1; off < 512; off <<= 1) {
        int i0 = tid, i1 = tid + 256;
        int v0 = (i0 >= off) ? sc[i0 - off] : 0;
        int v1 = (i1 >= off) ? sc[i1 - off] : 0;
        __syncthreads();
        sc[i0] += v0; sc[i1] += v1;
        __syncthreads();
    }
    {
        int b0 = tid, b1 = tid + 256;
        int o0 = sc[b0] - hist[b0];
        int o1 = sc[b1] - hist[b1];
        place[b0] = o0; place[b1] = o1;
        sc[b0] = o0; sc[b1] = o1;
        if (b0 < NBKT && hist[b0]) gbase[b0] = atomicAdd(&gcur[b0], hist[b0]);
        if (b1 < NBKT && hist[b1]) gbase[b1] = atomicAdd(&gcur[b1], hist[b1]);
    }
    __syncthreads();
    #pragma unroll
    for (int r = 0; r < 16; ++r) {
        if (bk[r] >= 0) {
            int p = atomicAdd(&place[bk[r]], 1);
            staging[p] = pay[r];
            bid[p] = (unsigned short)bk[r];
        }
    }
    __syncthreads();
    for (int i = tid; i < n; i += 256) {
        int b = bid[i];
        int gp = gbase[b] + (i - sc[b]);
        if (gp < CAP) slab[(size_t)b * CAP + gp] = staging[i];
    }
}

// Per bucket: histogram local dst, scan, reorder in LDS, write back in place
// (coalesced, sorted by dst). Emits rowptr/cnt/dis.
__global__ __launch_bounds__(512) void k_csr(const int* __restrict__ gcur,
                                             unsigned int* __restrict__ slab,
                                             int* __restrict__ rowptr,
                                             int* __restrict__ cnt,
                                             float* __restrict__ dis) {
    __shared__ int hist[BNODES];
    __shared__ int lofs[BNODES];
    __shared__ int place[BNODES];
    __shared__ unsigned int reord[CAP];
    int tid = threadIdx.x, b = blockIdx.x;
    if (tid < BNODES) hist[tid] = 0;
    __syncthreads();
    int count = min(gcur[b], CAP);
    unsigned int* sl = slab + (size_t)b * CAP;
    for (int i = tid; i < count; i += 512) atomicAdd(&hist[sl[i] >> 24], 1);
    __syncthreads();
    if (tid < BNODES) lofs[tid] = hist[tid];
    __syncthreads();
    for (int off = 1; off < BNODES; off <<= 1) {
        int v = 0;
        if (tid < BNODES && tid >= off) v = lofs[tid - off];
        __syncthreads();
        if (tid < BNODES) lofs[tid] += v;
        __syncthreads();
    }
    if (tid < BNODES) {
        int ex = lofs[tid] - hist[tid];
        lofs[tid] = ex;
        place[tid] = ex;
        int node = b * BNODES + tid;
        if (node < N_NODES) {
            rowptr[node] = b * CAP + ex;
            cnt[node] = hist[tid];
            dis[node] = rsqrtf((float)hist[tid] + 1.0f);
        }
    }
    __syncthreads();
    for (int i = tid; i < count; i += 512) {
        unsigned int v = sl[i];
        int dl = v >> 24;
        int p = atomicAdd(&place[dl], 1);
        reord[p] = v & 0xFFFFFFu;
    }
    __syncthreads();
    for (int i = tid; i < count; i += 512) sl[i] = reord[i];
}

// h1 = x @ W1, stored pre-scaled by dis[n] as packed bf16 pairs.
__global__ __launch_bounds__(256) void k_linear1(const float* __restrict__ x,
                                                 const float* __restrict__ W1,
                                                 const float* __restrict__ dis,
                                                 unsigned* __restrict__ hb) {
    __shared__ float Ws[F_INC * HIDC];
    for (int i = threadIdx.x; i < F_INC * HIDC; i += 256) Ws[i] = W1[i];
    __syncthreads();
    int n = blockIdx.x * blockDim.x + threadIdx.x;
    if (n >= N_NODES) return;
    float acc[HIDC];
    #pragma unroll
    for (int j = 0; j < HIDC; ++j) acc[j] = 0.f;
    const float4* xr = (const float4*)(x + (size_t)n * F_INC);
    for (int k4 = 0; k4 < F_INC / 4; ++k4) {
        float4 v = xr[k4];
        const float* w = &Ws[k4 * 4 * HIDC];
        #pragma unroll
        for (int j = 0; j < HIDC; ++j)
            acc[j] += v.x * w[j] + v.y * w[HIDC + j] + v.z * w[2 * HIDC + j] + v.w * w[3 * HIDC + j];
    }
    float dn = dis[n];
    unsigned o[8];
    #pragma unroll
    for (int q = 0; q < 8; ++q) o[q] = pack_bf2(dn * acc[2 * q], dn * acc[2 * q + 1]);
    uint4* ob = (uint4*)(hb + (size_t)n * 8);
    ob[0] = make_uint4(o[0], o[1], o[2], o[3]);
    ob[1] = make_uint4(o[4], o[5], o[6], o[7]);
}

// Pair-lane gather over pre-scaled bf16 table hb (hb[s] = dis[s]*h[s]):
//   agg[n] = dis[n] * ( hb[n] + sum_{s in in(n)} hb[s] )
// POST=0: store agg as f32 (float2 per lane). POST=1: z = elu(agg + bias),
// store pack_bf2(dis[n]*z) (next layer's pre-scaled table).
template<int POST>
__global__ __launch_bounds__(256) void k_gather8(const int* __restrict__ rowptr,
                                                 const int* __restrict__ cnt,
                                                 const unsigned* __restrict__ csr,
                                                 const float* __restrict__ dis,
                                                 const unsigned* __restrict__ hb,
                                                 void* __restrict__ outp,
                                                 const float* __restrict__ bias) {
    int idx = blockIdx.x * blockDim.x + threadIdx.x;
    int n = idx >> 3;
    if (n >= N_NODES) return;
    int q = idx & 7;
    int base = rowptr[n];
    int deg = cnt[n];
    unsigned sv = hb[(size_t)n * 8 + q];
    float acc0 = bflo(sv), acc1 = bfhi(sv);
    int j = 0;
    for (; j + 3 < deg; j += 4) {
        int s0 = csr[base + j];
        int s1 = csr[base + j + 1];
        int s2 = csr[base + j + 2];
        int s3 = csr[base + j + 3];
        unsigned v0 = hb[(size_t)s0 * 8 + q];
        unsigned v1 = hb[(size_t)s1 * 8 + q];
        unsigned v2 = hb[(size_t)s2 * 8 + q];
        unsigned v3 = hb[(size_t)s3 * 8 + q];
        acc0 += (bflo(v0) + bflo(v1)) + (bflo(v2) + bflo(v3));
        acc1 += (bfhi(v0) + bfhi(v1)) + (bfhi(v2) + bfhi(v3));
    }
    for (; j < deg; ++j) {
        int s = csr[base + j];
        unsigned v = hb[(size_t)s * 8 + q];
        acc0 += bflo(v);
        acc1 += bfhi(v);
    }
    float dn = dis[n];
    acc0 *= dn; acc1 *= dn;
    if (POST == 0) {
        ((float2*)outp)[(size_t)n * 8 + q] = make_float2(acc0, acc1);
    } else {
        float z0 = elu1(acc0 + bias[2 * q]);
        float z1 = elu1(acc1 + bias[2 * q + 1]);
        ((unsigned*)outp)[(size_t)n * 8 + q] = pack_bf2(dn * z0, dn * z1);
    }
}

// h2 = elu(agg1 + b1) @ W2, stored pre-scaled by dis[n] as packed bf16.
__global__ __launch_bounds__(256) void k_finlin16(const float* __restrict__ agg,
                                                  const float* __restrict__ bias,
                                                  const float* __restrict__ W,
                                                  const float* __restrict__ dis,
                                                  unsigned* __restrict__ hb) {
    __shared__ float Ws[HIDC * HIDC];
    __shared__ float bs[HIDC];
    for (int i = threadIdx.x; i < HIDC * HIDC; i += 256) Ws[i] = W[i];
    if (threadIdx.x < HIDC) bs[threadIdx.x] = bias[threadIdx.x];
    __syncthreads();
    int n = blockIdx.x * blockDim.x + threadIdx.x;
    if (n >= N_NODES) return;
    float act[HIDC];
    const float4* ar = (const float4*)(agg + (size_t)n * HIDC);
    #pragma unroll
    for (int k4 = 0; k4 < 4; ++k4) {
        float4 v = ar[k4];
        act[4 * k4 + 0] = elu1(v.x + bs[4 * k4 + 0]);
        act[4 * k4 + 1] = elu1(v.y + bs[4 * k4 + 1]);
        act[4 * k4 + 2] = elu1(v.z + bs[4 * k4 + 2]);
        act[4 * k4 + 3] = elu1(v.w + bs[4 * k4 + 3]);
    }
    float acc[HIDC];
    #pragma unroll
    for (int j = 0; j < HIDC; ++j) acc[j] = 0.f;
    #pragma unroll
    for (int k = 0; k < HIDC; ++k) {
        float a = act[k];
        #pragma unroll
        for (int j = 0; j < HIDC; ++j) acc[j] += a * Ws[k * HIDC + j];
    }
    float dn = dis[n];
    unsigned o[8];
    #pragma unroll
    for (int q = 0; q < 8; ++q) o[q] = pack_bf2(dn * acc[2 * q], dn * acc[2 * q + 1]);
    uint4* ob = (uint4*)(hb + (size_t)n * 8);
    ob[0] = make_uint4(o[0], o[1], o[2], o[3]);
    ob[1] = make_uint4(o[4], o[5], o[6], o[7]);
}

// out = log_softmax(elu(g @ W3 + b3)) per node; g = N(z2) [16-wide agg, f32].
__global__ __launch_bounds__(256) void k_final32(const float* __restrict__ g,
                                                 const float* __restrict__ W3,
                                                 const float* __restrict__ b3,
                                                 float* __restrict__ out) {
    __shared__ float Ws[HIDC * NCLS];
    __shared__ float bs[NCLS];
    for (int i = threadIdx.x; i < HIDC * NCLS; i += 256) Ws[i] = W3[i];
    if (threadIdx.x < NCLS) bs[threadIdx.x] = b3[threadIdx.x];
    __syncthreads();
    int n = blockIdx.x * blockDim.x + threadIdx.x;
    if (n >= N_NODES) return;
    float gv[HIDC];
    const float4* gr = (const float4*)(g + (size_t)n * HIDC);
    #pragma unroll
    for (int k4 = 0; k4 < 4; ++k4) {
        float4 v = gr[k4];
        gv[4 * k4 + 0] = v.x; gv[4 * k4 + 1] = v.y;
        gv[4 * k4 + 2] = v.z; gv[4 * k4 + 3] = v.w;
    }
    float r[NCLS];
    #pragma unroll
    for (int j = 0; j < NCLS; ++j) r[j] = bs[j];
    #pragma unroll
    for (int k = 0; k < HIDC; ++k) {
        float a = gv[k];
        #pragma unroll
        for (int j = 0; j < NCLS; ++j) r[j] += a * Ws[k * NCLS + j];
    }
    float m = -1e30f;
    #pragma unroll
    for (int j = 0; j < NCLS; ++j) { r[j] = elu1(r[j]); m = fmaxf(m, r[j]); }
    float ssum = 0.f;
    #pragma unroll
    for (int j = 0; j < NCLS; ++j) ssum += expf(r[j] - m);
    float lse = logf(ssum) + m;
    float4* o = (float4*)(out + (size_t)n * NCLS);
    #pragma unroll
    for (int j4 = 0; j4 < NCLS / 4; ++j4)
        o[j4] = make_float4(r[4 * j4] - lse, r[4 * j4 + 1] - lse,
                            r[4 * j4 + 2] - lse, r[4 * j4 + 3] - lse);
}

extern "C" void kernel_launch(void* const* d_in, const int* in_sizes, int n_in,
                              void* d_out, int out_size, void* d_ws, size_t ws_size,
                              hipStream_t stream) {
    const float* x  = (const float*)d_in[0];
    const int*   ei = (const int*)d_in[1];
    const float* W1 = (const float*)d_in[2];
    const float* b1 = (const float*)d_in[3];
    const float* W2 = (const float*)d_in[4];
    const float* b2 = (const float*)d_in[5];
    const float* W3 = (const float*)d_in[6];
    const float* b3 = (const float*)d_in[7];
    float* out = (float*)d_out;
    const int* src = ei;
    const int* dst = ei + N_EDGES;

    // workspace layout (4-byte elements)
    int* wi = (int*)d_ws;
    int*          gcur   = wi;                                   // 512
    unsigned int* slab   = (unsigned int*)(wi + 512);            // NBKT*CAP = 3,603,456
    int*          rowptr = wi + 512 + NBKT * CAP;                // 102,400
    int*          cnt    = rowptr + 102400;                      // 102,400
    float*        dis    = (float*)(cnt + 102400);               // 102,400
    unsigned*     Bh     = (unsigned*)(dis + 102400);            // 819,200 (N*8 bf16-pairs)
    unsigned*     Zb     = Bh + 819200;                          // 819,200
    float*        C      = (float*)(Zb + 819200);                // 1,638,400 (N*16 f32)
    (void)ws_size; (void)n_in; (void)in_sizes; (void)out_size;

    auto blocks = [](long long n) { return (int)((n + 255) / 256); };
    const int GNODE = blocks(N_NODES);                 // 391
    const int GGATH = blocks((long long)N_NODES * 8);  // 3125

    k_zero_cur<<<1, 512, 0, stream>>>(gcur);
    k_bucket<<<NCHUNK, 256, 0, stream>>>(src, dst, gcur, slab);
    k_csr<<<NBKT, 512, 0, stream>>>(gcur, slab, rowptr, cnt, dis);

    // Layer 1: h1 = x@W1 (pre-scaled bf16) -> a1 = N(h1)
    k_linear1<<<GNODE, 256, 0, stream>>>(x, W1, dis, Bh);
    k_gather8<0><<<GGATH, 256, 0, stream>>>(rowptr, cnt, slab, dis, Bh, C, nullptr);
    // h2 = elu(a1+b1)@W2 (pre-scaled bf16)
    k_finlin16<<<GNODE, 256, 0, stream>>>(C, b1, W2, dis, Bh);
    // Layer 2: a2 = N(h2); z2 = elu(a2+b2) stored pre-scaled bf16
    k_gather8<1><<<GGATH, 256, 0, stream>>>(rowptr, cnt, slab, dis, Bh, Zb, b2);
    // Layer 3: g = N(z2) [f32]; out = log_softmax(elu(g@W3 + b3))
    k_gather8<0><<<GGATH, 256, 0, stream>>>(rowptr, cnt, slab, dis, Zb, C, nullptr);
    k_final32<<<GNODE, 256, 0, stream>>>(C, W3, b3, out);
}